// Round 1
// baseline (204.420 us; speedup 1.0000x reference)
//
#include <hip/hip_runtime.h>
#include <hip/hip_bf16.h>
#include <stdint.h>

#define B_ROWS 8192
#define DIM 256
#define JCHUNK 1024
#define WPB 4  // waves per block
#define ROWS_PER_WAVE 32
#define ROWS_PER_BLOCK (WPB * ROWS_PER_WAVE)  // 128

typedef __bf16 bf16x8 __attribute__((ext_vector_type(8)));
typedef float f32x4 __attribute__((ext_vector_type(4)));

__device__ __forceinline__ unsigned short f2bf_rne(float f) {
    unsigned int u = __builtin_bit_cast(unsigned int, f);
    unsigned int r = (u + 0x7FFFu + ((u >> 16) & 1u)) >> 16;
    return (unsigned short)r;
}

// ---------------- Kernel 1: L2-normalize rows, emit bf16 ----------------
__global__ __launch_bounds__(64) void normalize_k(const float* __restrict__ emb,
                                                  unsigned short* __restrict__ ebf) {
    const int row = blockIdx.x;
    const int lane = threadIdx.x;  // 0..63, 4 floats each covers DIM=256
    const float4 v = reinterpret_cast<const float4*>(emb + (size_t)row * DIM)[lane];
    float ss = v.x * v.x + v.y * v.y + v.z * v.z + v.w * v.w;
    #pragma unroll
    for (int off = 32; off; off >>= 1) ss += __shfl_xor(ss, off);
    const float scale = 1.0f / fmaxf(sqrtf(ss), 1e-12f);
    ushort4 o;
    o.x = f2bf_rne(v.x * scale);
    o.y = f2bf_rne(v.y * scale);
    o.z = f2bf_rne(v.z * scale);
    o.w = f2bf_rne(v.w * scale);
    reinterpret_cast<ushort4*>(ebf + (size_t)row * DIM)[lane] = o;
}

// ---------------- Kernel 2: fused sim + masked exp-sum ----------------
// Each wave: 32 rows (2 A-tiles of 16), marches over a JCHUNK-wide column slice
// in 16-col MFMA tiles. Fixed max M = 1/0.07 (dot <= 1) => no online softmax.
__global__ __launch_bounds__(256) void sim_k(const unsigned short* __restrict__ ebf,
                                             const int* __restrict__ labels,
                                             float* __restrict__ Sall,
                                             float* __restrict__ Spos) {
    constexpr float INV_T = 1.0f / 0.07f;
    const int tid  = threadIdx.x;
    const int wave = tid >> 6;
    const int lane = tid & 63;
    const int col  = lane & 15;
    const int quad = lane >> 4;

    const int jblocks = B_ROWS / JCHUNK;           // 8
    const int rowblk  = blockIdx.x / jblocks;      // 0..63
    const int jblk    = blockIdx.x % jblocks;
    const int i_base  = rowblk * ROWS_PER_BLOCK + wave * ROWS_PER_WAVE;
    const int j0      = jblk * JCHUNK;

    // Preload A-fragments (2 tiles x 8 K-steps) and row labels.
    // Fragment layout (16x16x32 bf16): lane L holds row (L&15), dims kk*32+(L>>4)*8+[0..8)
    bf16x8 afrag[2][8];
    int li[2][4];
    #pragma unroll
    for (int t = 0; t < 2; ++t) {
        const int arow = i_base + t * 16 + col;
        const uint4* ap = reinterpret_cast<const uint4*>(ebf) + (size_t)arow * 32 + quad;
        #pragma unroll
        for (int kk = 0; kk < 8; ++kk)
            afrag[t][kk] = __builtin_bit_cast(bf16x8, ap[kk * 4]);
        #pragma unroll
        for (int r = 0; r < 4; ++r)
            li[t][r] = labels[i_base + t * 16 + quad * 4 + r];
    }

    float s_all[2][4] = {};
    float s_pos[2][4] = {};

    for (int jt = 0; jt < JCHUNK / 16; ++jt) {
        const int jcol = j0 + jt * 16 + col;
        const uint4* bp = reinterpret_cast<const uint4*>(ebf) + (size_t)jcol * 32 + quad;
        bf16x8 bfrag[8];
        #pragma unroll
        for (int kk = 0; kk < 8; ++kk)
            bfrag[kk] = __builtin_bit_cast(bf16x8, bp[kk * 4]);
        const int lj = labels[jcol];

        f32x4 acc0 = {0.f, 0.f, 0.f, 0.f};
        f32x4 acc1 = {0.f, 0.f, 0.f, 0.f};
        #pragma unroll
        for (int kk = 0; kk < 8; ++kk) {
            acc0 = __builtin_amdgcn_mfma_f32_16x16x32_bf16(afrag[0][kk], bfrag[kk], acc0, 0, 0, 0);
            acc1 = __builtin_amdgcn_mfma_f32_16x16x32_bf16(afrag[1][kk], bfrag[kk], acc1, 0, 0, 0);
        }

        // Epilogue: D[row=(quad*4+r)][col], exp((dot-1)/T), mask diag & positives
        #pragma unroll
        for (int t = 0; t < 2; ++t) {
            const f32x4 acc = t ? acc1 : acc0;
            #pragma unroll
            for (int r = 0; r < 4; ++r) {
                const int irow = i_base + t * 16 + quad * 4 + r;
                const float ex = __expf(fmaf(acc[r], INV_T, -INV_T));
                const bool valid = (jcol != irow);
                const bool pos = valid && (lj == li[t][r]);
                s_all[t][r] += valid ? ex : 0.0f;
                s_pos[t][r] += pos ? ex : 0.0f;
            }
        }
    }

    // Reduce over the 16 column-lanes within each quad, then one atomic per row.
    #pragma unroll
    for (int t = 0; t < 2; ++t) {
        #pragma unroll
        for (int r = 0; r < 4; ++r) {
            float a = s_all[t][r];
            float p = s_pos[t][r];
            #pragma unroll
            for (int off = 1; off < 16; off <<= 1) {
                a += __shfl_xor(a, off);
                p += __shfl_xor(p, off);
            }
            if (col == 0) {
                const int irow = i_base + t * 16 + quad * 4 + r;
                atomicAdd(&Sall[irow], a);
                atomicAdd(&Spos[irow], p);
            }
        }
    }
}

// ---------------- Kernel 3: per-row loss + mean ----------------
__global__ __launch_bounds__(256) void finalize_k(const float* __restrict__ Sall,
                                                  const float* __restrict__ Spos,
                                                  float* __restrict__ out) {
    const int tid = threadIdx.x;
    float sum = 0.0f;
    int cnt = 0;
    for (int i = tid; i < B_ROWS; i += 256) {
        const float sp = Spos[i];
        if (sp > 0.0f) {
            sum += logf(Sall[i]) - logf(sp);  // M cancels
            ++cnt;
        }
    }
    #pragma unroll
    for (int off = 32; off; off >>= 1) {
        sum += __shfl_xor(sum, off);
        cnt += __shfl_xor(cnt, off);
    }
    __shared__ float ssum[WPB];
    __shared__ int scnt[WPB];
    const int wave = tid >> 6, lane = tid & 63;
    if (lane == 0) { ssum[wave] = sum; scnt[wave] = cnt; }
    __syncthreads();
    if (tid == 0) {
        float s = 0.0f;
        int c = 0;
        #pragma unroll
        for (int w = 0; w < WPB; ++w) { s += ssum[w]; c += scnt[w]; }
        out[0] = (c > 0) ? s / (float)c : 0.0f;
    }
}

extern "C" void kernel_launch(void* const* d_in, const int* in_sizes, int n_in,
                              void* d_out, int out_size, void* d_ws, size_t ws_size,
                              hipStream_t stream) {
    const float* emb   = (const float*)d_in[0];
    const int* labels  = (const int*)d_in[1];
    float* out         = (float*)d_out;

    unsigned short* ebf = (unsigned short*)d_ws;                       // 4 MB bf16 normalized
    float* Sall = (float*)((char*)d_ws + (size_t)B_ROWS * DIM * 2);    // 32 KB
    float* Spos = Sall + B_ROWS;                                       // 32 KB

    hipMemsetAsync(Sall, 0, 2 * B_ROWS * sizeof(float), stream);

    normalize_k<<<B_ROWS, 64, 0, stream>>>(emb, ebf);

    dim3 grid((B_ROWS / ROWS_PER_BLOCK) * (B_ROWS / JCHUNK));          // 64*8 = 512
    sim_k<<<grid, 256, 0, stream>>>(ebf, labels, Sall, Spos);

    finalize_k<<<1, 256, 0, stream>>>(Sall, Spos, out);
}

// Round 2
// 135.743 us; speedup vs baseline: 1.5059x; 1.5059x over previous
//
#include <hip/hip_runtime.h>
#include <hip/hip_bf16.h>
#include <stdint.h>

#define B_ROWS 8192
#define DIM 256
#define JCHUNK 512
#define WPB 4  // waves per block
#define ROWS_PER_WAVE 32
#define ROWS_PER_BLOCK (WPB * ROWS_PER_WAVE)  // 128
#define NT (JCHUNK / 16)                      // 32 j-tiles per block

typedef __bf16 bf16x8 __attribute__((ext_vector_type(8)));
typedef float f32x4 __attribute__((ext_vector_type(4)));

__device__ __forceinline__ unsigned short f2bf_rne(float f) {
    unsigned int u = __builtin_bit_cast(unsigned int, f);
    unsigned int r = (u + 0x7FFFu + ((u >> 16) & 1u)) >> 16;
    return (unsigned short)r;
}

// ---------------- Kernel 1: L2-normalize rows, emit bf16 ----------------
// 4 rows per 256-thread block (one row per wave).
__global__ __launch_bounds__(256) void normalize_k(const float* __restrict__ emb,
                                                   unsigned short* __restrict__ ebf) {
    const int row = blockIdx.x * 4 + (threadIdx.x >> 6);
    const int lane = threadIdx.x & 63;  // 4 floats each covers DIM=256
    const float4 v = reinterpret_cast<const float4*>(emb + (size_t)row * DIM)[lane];
    float ss = v.x * v.x + v.y * v.y + v.z * v.z + v.w * v.w;
    #pragma unroll
    for (int off = 32; off; off >>= 1) ss += __shfl_xor(ss, off);
    const float scale = 1.0f / fmaxf(sqrtf(ss), 1e-12f);
    ushort4 o;
    o.x = f2bf_rne(v.x * scale);
    o.y = f2bf_rne(v.y * scale);
    o.z = f2bf_rne(v.z * scale);
    o.w = f2bf_rne(v.w * scale);
    reinterpret_cast<ushort4*>(ebf + (size_t)row * DIM)[lane] = o;
}

// ---------------- Kernel 2: fused sim + masked exp-sum ----------------
// A (32 rows/wave, full K=256) register-resident. B-tile (16 cols x 512B = 8KB)
// staged in LDS per block, double-buffered, XOR-swizzled so the MFMA-fragment
// ds_read_b128 pattern is conflict-free (2-way). Fixed max M = 1/0.07.
__global__ __launch_bounds__(256, 3) void sim_k(const unsigned short* __restrict__ ebf,
                                                const int* __restrict__ labels,
                                                float* __restrict__ Sall,
                                                float* __restrict__ Spos) {
    constexpr float INV_T = 1.0f / 0.07f;
    __shared__ __align__(16) unsigned char lds[2][8192];

    const int tid  = threadIdx.x;
    const int wave = tid >> 6;
    const int lane = tid & 63;
    const int col  = lane & 15;
    const int quad = lane >> 4;

    const int jblocks = B_ROWS / JCHUNK;           // 16
    const int rowblk  = blockIdx.x / jblocks;      // 0..63
    const int jblk    = blockIdx.x % jblocks;
    const int i_base  = rowblk * ROWS_PER_BLOCK + wave * ROWS_PER_WAVE;
    const int j0      = jblk * JCHUNK;

    // ---- Preload A-fragments (2 tiles x 8 K-steps) + row labels ----
    // lane L holds A[row = L&15][k = kk*32 + (L>>4)*8 + 0..7]
    bf16x8 afrag[2][8];
    int li[2][4];
    #pragma unroll
    for (int t = 0; t < 2; ++t) {
        const int arow = i_base + t * 16 + col;
        const uint4* ap = reinterpret_cast<const uint4*>(ebf) + (size_t)arow * 32 + quad;
        #pragma unroll
        for (int kk = 0; kk < 8; ++kk)
            afrag[t][kk] = __builtin_bit_cast(bf16x8, ap[kk * 4]);
        #pragma unroll
        for (int r = 0; r < 4; ++r)
            li[t][r] = labels[i_base + t * 16 + quad * 4 + r];
    }

    // ---- Staging geometry ----
    // Tile = 16 rows x 512B. 16B chunks; chunk c of row r stored at r*512 + ((c^r)&31)*16.
    // 256 threads x 2 rounds x 16B = 8KB. Round rd: row = rd*8 + tid/32, c = tid&31.
    const int st_r = tid >> 5;      // 0..7
    const int st_c = tid & 31;
    const uint4* gB = reinterpret_cast<const uint4*>(ebf);

    // stage tile 0 into lds[0]
    {
        const uint4 v0 = gB[(size_t)(j0 + st_r) * 32 + st_c];
        const uint4 v1 = gB[(size_t)(j0 + 8 + st_r) * 32 + st_c];
        *reinterpret_cast<uint4*>(&lds[0][st_r * 512 + ((st_c ^ st_r) & 31) * 16]) = v0;
        *reinterpret_cast<uint4*>(&lds[0][(8 + st_r) * 512 + ((st_c ^ (8 + st_r)) & 31) * 16]) = v1;
    }
    __syncthreads();

    float s_all[2][4] = {};
    float s_pos[2][4] = {};

    int cur = 0;
    for (int jt = 0; jt < NT; ++jt) {
        // prefetch next tile's global data (uniform branch)
        uint4 p0, p1;
        const bool havenext = (jt + 1) < NT;
        if (havenext) {
            const int jn = j0 + (jt + 1) * 16;
            p0 = gB[(size_t)(jn + st_r) * 32 + st_c];
            p1 = gB[(size_t)(jn + 8 + st_r) * 32 + st_c];
        }

        // read B-fragments from LDS (swizzled)
        bf16x8 bfrag[8];
        #pragma unroll
        for (int kk = 0; kk < 8; ++kk) {
            const int c = kk * 4 + quad;
            bfrag[kk] = *reinterpret_cast<const bf16x8*>(
                &lds[cur][col * 512 + ((c ^ col) & 31) * 16]);
        }
        const int jcol = j0 + jt * 16 + col;
        const int lj = labels[jcol];

        f32x4 acc0 = {0.f, 0.f, 0.f, 0.f};
        f32x4 acc1 = {0.f, 0.f, 0.f, 0.f};
        #pragma unroll
        for (int kk = 0; kk < 8; ++kk) {
            acc0 = __builtin_amdgcn_mfma_f32_16x16x32_bf16(afrag[0][kk], bfrag[kk], acc0, 0, 0, 0);
            acc1 = __builtin_amdgcn_mfma_f32_16x16x32_bf16(afrag[1][kk], bfrag[kk], acc1, 0, 0, 0);
        }

        // Epilogue. D[row = quad*4+r][col]. Wave-uniform: diagonal only possible
        // when this 16-col strip overlaps the wave's 32-row strip.
        const int jt16 = j0 + jt * 16;
        const bool diag_possible = (jt16 < i_base + 32) && (i_base < jt16 + 16);
        if (!diag_possible) {
            #pragma unroll
            for (int t = 0; t < 2; ++t) {
                const f32x4 acc = t ? acc1 : acc0;
                #pragma unroll
                for (int r = 0; r < 4; ++r) {
                    const float ex = __expf(fmaf(acc[r], INV_T, -INV_T));
                    s_all[t][r] += ex;
                    s_pos[t][r] += (lj == li[t][r]) ? ex : 0.0f;
                }
            }
        } else {
            #pragma unroll
            for (int t = 0; t < 2; ++t) {
                const f32x4 acc = t ? acc1 : acc0;
                #pragma unroll
                for (int r = 0; r < 4; ++r) {
                    const int irow = i_base + t * 16 + quad * 4 + r;
                    const float ex = __expf(fmaf(acc[r], INV_T, -INV_T));
                    const bool valid = (jcol != irow);
                    const bool pos = valid && (lj == li[t][r]);
                    s_all[t][r] += valid ? ex : 0.0f;
                    s_pos[t][r] += pos ? ex : 0.0f;
                }
            }
        }

        // write prefetched tile into the other buffer, then barrier
        if (havenext) {
            unsigned char* dst = lds[cur ^ 1];
            *reinterpret_cast<uint4*>(&dst[st_r * 512 + ((st_c ^ st_r) & 31) * 16]) = p0;
            *reinterpret_cast<uint4*>(&dst[(8 + st_r) * 512 + ((st_c ^ (8 + st_r)) & 31) * 16]) = p1;
        }
        __syncthreads();
        cur ^= 1;
    }

    // Reduce over the 16 column-lanes within each quad, then one atomic per row.
    #pragma unroll
    for (int t = 0; t < 2; ++t) {
        #pragma unroll
        for (int r = 0; r < 4; ++r) {
            float a = s_all[t][r];
            float p = s_pos[t][r];
            #pragma unroll
            for (int off = 1; off < 16; off <<= 1) {
                a += __shfl_xor(a, off);
                p += __shfl_xor(p, off);
            }
            if (col == 0) {
                const int irow = i_base + t * 16 + quad * 4 + r;
                atomicAdd(&Sall[irow], a);
                atomicAdd(&Spos[irow], p);
            }
        }
    }
}

// ---------------- Kernel 3: per-row loss + mean ----------------
__global__ __launch_bounds__(256) void finalize_k(const float* __restrict__ Sall,
                                                  const float* __restrict__ Spos,
                                                  float* __restrict__ out) {
    const int tid = threadIdx.x;
    float sum = 0.0f;
    int cnt = 0;
    for (int i = tid; i < B_ROWS; i += 256) {
        const float sp = Spos[i];
        if (sp > 0.0f) {
            sum += logf(Sall[i]) - logf(sp);  // fixed max M cancels
            ++cnt;
        }
    }
    #pragma unroll
    for (int off = 32; off; off >>= 1) {
        sum += __shfl_xor(sum, off);
        cnt += __shfl_xor(cnt, off);
    }
    __shared__ float ssum[WPB];
    __shared__ int scnt[WPB];
    const int wave = tid >> 6, lane = tid & 63;
    if (lane == 0) { ssum[wave] = sum; scnt[wave] = cnt; }
    __syncthreads();
    if (tid == 0) {
        float s = 0.0f;
        int c = 0;
        #pragma unroll
        for (int w = 0; w < WPB; ++w) { s += ssum[w]; c += scnt[w]; }
        out[0] = (c > 0) ? s / (float)c : 0.0f;
    }
}

extern "C" void kernel_launch(void* const* d_in, const int* in_sizes, int n_in,
                              void* d_out, int out_size, void* d_ws, size_t ws_size,
                              hipStream_t stream) {
    const float* emb   = (const float*)d_in[0];
    const int* labels  = (const int*)d_in[1];
    float* out         = (float*)d_out;

    unsigned short* ebf = (unsigned short*)d_ws;                       // 4 MB bf16 normalized
    float* Sall = (float*)((char*)d_ws + (size_t)B_ROWS * DIM * 2);    // 32 KB
    float* Spos = Sall + B_ROWS;                                       // 32 KB

    hipMemsetAsync(Sall, 0, 2 * B_ROWS * sizeof(float), stream);

    normalize_k<<<B_ROWS / 4, 256, 0, stream>>>(emb, ebf);

    dim3 grid((B_ROWS / ROWS_PER_BLOCK) * (B_ROWS / JCHUNK));          // 64*16 = 1024
    sim_k<<<grid, 256, 0, stream>>>(ebf, labels, Sall, Spos);

    finalize_k<<<1, 256, 0, stream>>>(Sall, Spos, out);
}